// Round 3
// baseline (552.454 us; speedup 1.0000x reference)
//
#include <hip/hip_runtime.h>

#define K_ 4096
#define N_ 4096
#define M_ 8192
#define NOUT_ 128
#define NT_ (K_ / 64)

typedef __bf16 bf16x8 __attribute__((ext_vector_type(8)));
typedef float f32x4 __attribute__((ext_vector_type(4)));
typedef unsigned short ushort8 __attribute__((ext_vector_type(8)));

__device__ __forceinline__ unsigned short f2bf(float f) {
  unsigned u = __builtin_bit_cast(unsigned, f);
  u += 0x7fffu + ((u >> 16) & 1u);   // round-to-nearest-even
  return (unsigned short)(u >> 16);
}

// ---- kernel 1: x fp32 -> bf16 (8 elems/thread) ----
__global__ void cvt_x_kernel(const float4* __restrict__ x4, ushort8* __restrict__ xb) {
  const int t = blockIdx.x * 256 + threadIdx.x;
  float4 a = x4[2 * t];
  float4 b = x4[2 * t + 1];
  ushort8 o;
  o[0] = f2bf(a.x); o[1] = f2bf(a.y); o[2] = f2bf(a.z); o[3] = f2bf(a.w);
  o[4] = f2bf(b.x); o[5] = f2bf(b.y); o[6] = f2bf(b.z); o[7] = f2bf(b.w);
  xb[t] = o;
}

// ---- kernel 2: dequant W + fold outlier weights into last 128 k-columns ----
__global__ void dequant_kernel(const int4* __restrict__ q4,
                               const float* __restrict__ scales,
                               const float* __restrict__ zeros,
                               const float* __restrict__ ow,
                               ushort8* __restrict__ wb) {
  const int t = blockIdx.x * 256 + threadIdx.x;  // N*K/8 threads
  const int n = t >> 9;            // K/8 = 512 chunks per row
  const int k = (t & 511) << 3;
  const int g = k >> 7;            // group = k/128
  const float s = scales[g * N_ + n];
  const float z = zeros[g * N_ + n];
  int4 qa = q4[2 * t], qb = q4[2 * t + 1];
  float f[8];
  f[0] = qa.x * s + z; f[1] = qa.y * s + z; f[2] = qa.z * s + z; f[3] = qa.w * s + z;
  f[4] = qb.x * s + z; f[5] = qb.y * s + z; f[6] = qb.z * s + z; f[7] = qb.w * s + z;
  if (k >= K_ - NOUT_) {
    const float4* o4 = (const float4*)(ow + n * NOUT_ + (k - (K_ - NOUT_)));
    float4 oa = o4[0], ob = o4[1];
    f[0] += oa.x; f[1] += oa.y; f[2] += oa.z; f[3] += oa.w;
    f[4] += ob.x; f[5] += ob.y; f[6] += ob.z; f[7] += ob.w;
  }
  ushort8 r;
  #pragma unroll
  for (int i = 0; i < 8; ++i) r[i] = f2bf(f[i]);
  wb[t] = r;
}

// ---- kernel 3: 256x256 tile, 8-wave (2x4), BK=64, deep-pipelined MFMA GEMM ----
// Double-buffered 128 KiB LDS; per K-tile: issue next tile's 8 global_load_lds,
// counted s_waitcnt vmcnt(8) (prefetch stays in flight across the barrier),
// 4 barriered phases x 16 MFMA with s_setprio around the MFMA clusters.
// Chunk-XOR swizzle: LDS stays linear for global_load_lds; the global SOURCE is
// pre-inverse-swizzled; ds_read applies the same XOR. (0 bank conflicts, proven.)
#define STAGE(dA, dB, kof)                                                          \
  do {                                                                              \
    _Pragma("unroll") for (int i_ = 0; i_ < 4; ++i_)                                \
        __builtin_amdgcn_global_load_lds(                                           \
            (__attribute__((address_space(1))) void*)(gA[i_] + (kof)),              \
            (__attribute__((address_space(3))) void*)((dA) + aoff[i_]), 16, 0, 0);  \
    _Pragma("unroll") for (int i_ = 0; i_ < 4; ++i_)                                \
        __builtin_amdgcn_global_load_lds(                                           \
            (__attribute__((address_space(1))) void*)(gB[i_] + (kof)),              \
            (__attribute__((address_space(3))) void*)((dB) + aoff[i_]), 16, 0, 0);  \
  } while (0)

__global__ __launch_bounds__(512, 2) void gemm_kernel(
    const unsigned short* __restrict__ xb,
    const unsigned short* __restrict__ wb,
    const float* __restrict__ bias,
    float* __restrict__ out) {
  // [0,32K): A buf0  [32K,64K): A buf1  [64K,96K): B buf0  [96K,128K): B buf1
  __shared__ __attribute__((aligned(16))) char lds[131072];

  const int tid  = threadIdx.x;
  const int w    = tid >> 6;      // 0..7
  const int lane = tid & 63;
  const int q    = lane >> 4;
  const int l16  = lane & 15;
  const int wr   = w >> 2;        // 0..1  (M half)
  const int wc   = w & 3;         // 0..3  (N quarter)

  // XCD-aware bijective swizzle (512 wgs, divisible by 8)
  const int id  = blockIdx.y * 16 + blockIdx.x;   // gridDim = (16, 32)
  const int id2 = (id & 7) * 64 + (id >> 3);
  const int m0  = (id2 >> 4) * 256;
  const int n0  = (id2 & 15) * 256;

  // staging addresses: wave w, issue i covers linear bytes [i*8192+w*1024, +1024)
  const unsigned short* gA[4];
  const unsigned short* gB[4];
  int aoff[4];
  #pragma unroll
  for (int i = 0; i < 4; ++i) {
    const int o  = i * 8192 + w * 1024 + lane * 16;  // linear byte offset in 32 KiB tile
    const int r  = o >> 7;                            // row (128 B rows)
    const int cs = (o >> 4) & 7;                      // LDS slot this lane fills
    const int cg = cs ^ (r & 7);                      // global chunk that belongs there
    gA[i] = xb + (size_t)(m0 + r) * K_ + cg * 8;
    gB[i] = wb + (size_t)(n0 + r) * K_ + cg * 8;
    aoff[i] = i * 8192 + w * 1024;                    // wave-uniform LDS byte offset
  }

  const char* pA0 = lds + (wr * 128 + l16) * 128;           // A row base (m-frag 0)
  const char* pB0 = lds + 65536 + (wc * 64 + l16) * 128;    // B row base (n-frag 0)
  const int sl0 = ((0 + q) ^ (l16 & 7)) * 16;   // k-slice 0: chunks 0..3
  const int sl1 = ((4 + q) ^ (l16 & 7)) * 16;   // k-slice 1: chunks 4..7

  f32x4 acc[8][4] = {};

  // prologue: stage tile 0 into buf0
  STAGE((char*)lds, (char*)lds + 65536, 0);

  for (int t = 0; t < NT_; ++t) {
    const int curo = (t & 1) * 32768;
    const char* cA = pA0 + curo;
    const char* cB = pB0 + curo;

    if (t + 1 < NT_) {
      char* dA = (char*)lds + (((t + 1) & 1) * 32768);
      char* dB = (char*)lds + 65536 + (((t + 1) & 1) * 32768);
      STAGE(dA, dB, (t + 1) * 64);
      asm volatile("s_waitcnt vmcnt(8)" ::: "memory");  // wait tile t; 8 prefetch stay in flight
    } else {
      asm volatile("s_waitcnt vmcnt(0)" ::: "memory");
    }
    __builtin_amdgcn_s_barrier();          // tile t ready for everyone
    __builtin_amdgcn_sched_barrier(0);

    bf16x8 a[4][2], b0[2][2], b1[2][2];

    // ---- phase 0: (mh=0, nh=0)  reads a-half0 + b-half0 ----
    #pragma unroll
    for (int f = 0; f < 4; ++f) {
      a[f][0] = *(const bf16x8*)(cA + f * 2048 + sl0);
      a[f][1] = *(const bf16x8*)(cA + f * 2048 + sl1);
    }
    #pragma unroll
    for (int j = 0; j < 2; ++j) {
      b0[j][0] = *(const bf16x8*)(cB + j * 2048 + sl0);
      b0[j][1] = *(const bf16x8*)(cB + j * 2048 + sl1);
    }
    __builtin_amdgcn_s_barrier();
    __builtin_amdgcn_s_setprio(1);
    #pragma unroll
    for (int f = 0; f < 4; ++f)
      #pragma unroll
      for (int j = 0; j < 2; ++j) {
        acc[f][j] = __builtin_amdgcn_mfma_f32_16x16x32_bf16(a[f][0], b0[j][0], acc[f][j], 0, 0, 0);
        acc[f][j] = __builtin_amdgcn_mfma_f32_16x16x32_bf16(a[f][1], b0[j][1], acc[f][j], 0, 0, 0);
      }
    __builtin_amdgcn_s_setprio(0);
    __builtin_amdgcn_s_barrier();

    // ---- phase 1: (mh=0, nh=1)  reads b-half1, reuses a ----
    #pragma unroll
    for (int j = 0; j < 2; ++j) {
      b1[j][0] = *(const bf16x8*)(cB + (2 + j) * 2048 + sl0);
      b1[j][1] = *(const bf16x8*)(cB + (2 + j) * 2048 + sl1);
    }
    __builtin_amdgcn_s_barrier();
    __builtin_amdgcn_s_setprio(1);
    #pragma unroll
    for (int f = 0; f < 4; ++f)
      #pragma unroll
      for (int j = 0; j < 2; ++j) {
        acc[f][2 + j] = __builtin_amdgcn_mfma_f32_16x16x32_bf16(a[f][0], b1[j][0], acc[f][2 + j], 0, 0, 0);
        acc[f][2 + j] = __builtin_amdgcn_mfma_f32_16x16x32_bf16(a[f][1], b1[j][1], acc[f][2 + j], 0, 0, 0);
      }
    __builtin_amdgcn_s_setprio(0);
    __builtin_amdgcn_s_barrier();

    // ---- phase 2: (mh=1, nh=0)  reads a-half1, reuses b0 ----
    #pragma unroll
    for (int f = 0; f < 4; ++f) {
      a[f][0] = *(const bf16x8*)(cA + (4 + f) * 2048 + sl0);
      a[f][1] = *(const bf16x8*)(cA + (4 + f) * 2048 + sl1);
    }
    __builtin_amdgcn_s_barrier();
    __builtin_amdgcn_s_setprio(1);
    #pragma unroll
    for (int f = 0; f < 4; ++f)
      #pragma unroll
      for (int j = 0; j < 2; ++j) {
        acc[4 + f][j] = __builtin_amdgcn_mfma_f32_16x16x32_bf16(a[f][0], b0[j][0], acc[4 + f][j], 0, 0, 0);
        acc[4 + f][j] = __builtin_amdgcn_mfma_f32_16x16x32_bf16(a[f][1], b0[j][1], acc[4 + f][j], 0, 0, 0);
      }
    __builtin_amdgcn_s_setprio(0);
    __builtin_amdgcn_s_barrier();

    // ---- phase 3: (mh=1, nh=1)  no reads, reuses a + b1 ----
    __builtin_amdgcn_s_setprio(1);
    #pragma unroll
    for (int f = 0; f < 4; ++f)
      #pragma unroll
      for (int j = 0; j < 2; ++j) {
        acc[4 + f][2 + j] = __builtin_amdgcn_mfma_f32_16x16x32_bf16(a[f][0], b1[j][0], acc[4 + f][2 + j], 0, 0, 0);
        acc[4 + f][2 + j] = __builtin_amdgcn_mfma_f32_16x16x32_bf16(a[f][1], b1[j][1], acc[4 + f][2 + j], 0, 0, 0);
      }
    __builtin_amdgcn_s_setprio(0);
    __builtin_amdgcn_s_barrier();   // m201 barrier skeleton: close the K-tile
  }

  float bv[4];
  #pragma unroll
  for (int j = 0; j < 4; ++j)
    bv[j] = bias[n0 + wc * 64 + j * 16 + l16];

  // C/D layout: col = lane&15, row = (lane>>4)*4 + reg  [m89/m91 verified]
  #pragma unroll
  for (int i = 0; i < 8; ++i) {
    const int mrow = m0 + wr * 128 + i * 16 + q * 4;
    #pragma unroll
    for (int j = 0; j < 4; ++j) {
      const int n = n0 + wc * 64 + j * 16 + l16;
      float* op = out + (size_t)mrow * N_ + n;
      #pragma unroll
      for (int r = 0; r < 4; ++r)
        op[(size_t)r * N_] = acc[i][j][r] + bv[j];
    }
  }
}

extern "C" void kernel_launch(void* const* d_in, const int* in_sizes, int n_in,
                              void* d_out, int out_size, void* d_ws, size_t ws_size,
                              hipStream_t stream) {
  const float* x      = (const float*)d_in[0];
  const int*   qw     = (const int*)d_in[1];
  const float* scales = (const float*)d_in[2];
  const float* zeros  = (const float*)d_in[3];
  const float* ow     = (const float*)d_in[4];
  const float* bias   = (const float*)d_in[5];
  float* out = (float*)d_out;

  unsigned short* xb = (unsigned short*)d_ws;            // 64 MiB
  unsigned short* wb = xb + (size_t)M_ * K_;             // +32 MiB

  cvt_x_kernel<<<(M_ * K_ / 8) / 256, 256, 0, stream>>>((const float4*)x, (ushort8*)xb);
  dequant_kernel<<<(N_ * K_ / 8) / 256, 256, 0, stream>>>((const int4*)qw, scales, zeros, ow,
                                                          (ushort8*)wb);
  dim3 grid(N_ / 256, M_ / 256);
  gemm_kernel<<<grid, 512, 0, stream>>>(xb, wb, bias, out);
}

// Round 4
// 495.925 us; speedup vs baseline: 1.1140x; 1.1140x over previous
//
#include <hip/hip_runtime.h>

#define K_ 4096
#define N_ 4096
#define M_ 8192
#define NOUT_ 128
#define NT_ (K_ / 64)

typedef __bf16 bf16x8 __attribute__((ext_vector_type(8)));
typedef float f32x4 __attribute__((ext_vector_type(4)));
typedef unsigned short ushort8 __attribute__((ext_vector_type(8)));

__device__ __forceinline__ unsigned short f2bf(float f) {
  unsigned u = __builtin_bit_cast(unsigned, f);
  u += 0x7fffu + ((u >> 16) & 1u);   // round-to-nearest-even
  return (unsigned short)(u >> 16);
}

// ---- kernel 1: x fp32 -> bf16 (8 elems/thread) ----
__global__ void cvt_x_kernel(const float4* __restrict__ x4, ushort8* __restrict__ xb) {
  const int t = blockIdx.x * 256 + threadIdx.x;
  float4 a = x4[2 * t];
  float4 b = x4[2 * t + 1];
  ushort8 o;
  o[0] = f2bf(a.x); o[1] = f2bf(a.y); o[2] = f2bf(a.z); o[3] = f2bf(a.w);
  o[4] = f2bf(b.x); o[5] = f2bf(b.y); o[6] = f2bf(b.z); o[7] = f2bf(b.w);
  xb[t] = o;
}

// ---- kernel 2: dequant W + fold outlier weights into last 128 k-columns ----
__global__ void dequant_kernel(const int4* __restrict__ q4,
                               const float* __restrict__ scales,
                               const float* __restrict__ zeros,
                               const float* __restrict__ ow,
                               ushort8* __restrict__ wb) {
  const int t = blockIdx.x * 256 + threadIdx.x;  // N*K/8 threads
  const int n = t >> 9;            // K/8 = 512 chunks per row
  const int k = (t & 511) << 3;
  const int g = k >> 7;            // group = k/128
  const float s = scales[g * N_ + n];
  const float z = zeros[g * N_ + n];
  int4 qa = q4[2 * t], qb = q4[2 * t + 1];
  float f[8];
  f[0] = qa.x * s + z; f[1] = qa.y * s + z; f[2] = qa.z * s + z; f[3] = qa.w * s + z;
  f[4] = qb.x * s + z; f[5] = qb.y * s + z; f[6] = qb.z * s + z; f[7] = qb.w * s + z;
  if (k >= K_ - NOUT_) {
    const float4* o4 = (const float4*)(ow + n * NOUT_ + (k - (K_ - NOUT_)));
    float4 oa = o4[0], ob = o4[1];
    f[0] += oa.x; f[1] += oa.y; f[2] += oa.z; f[3] += oa.w;
    f[4] += ob.x; f[5] += ob.y; f[6] += ob.z; f[7] += ob.w;
  }
  ushort8 r;
  #pragma unroll
  for (int i = 0; i < 8; ++i) r[i] = f2bf(f[i]);
  wb[t] = r;
}

// ---- kernel 3: 256x256 tile, 8-wave (2x4), BK=64, fine-grained 4-phase GEMM ----
// m201-style schedule. Stage unit = 128 rows x 64 k = 16 KiB, 2 global_load_lds
// per wave per unit. 1 unit staged PER PHASE, interleaved with that phase's
// ds_reads; vmcnt(6) once per K-tile (3 units in flight across barriers).
// Per-wave per K-tile: ph1 reads ALL B (8xb128) + A-low (8), ph3 reads A-high
// (8); B held in regs for the whole K-tile. Phases = C-quadrant x K=64, 16 MFMA.
// Stage order during tile t: ph1:(t+1).A1  ph2:(t+2).B0  ph3:(t+2).B1
// ph4:(t+2).A0  — every overwrite lands >=1 barrier after victim's last read.
// Chunk-XOR swizzle (slot = chunk ^ (row&7)) identical to the verified kernel.
#define AS1 __attribute__((address_space(1)))
#define AS3 __attribute__((address_space(3)))

#define STAGE_A(h, kt, ubase)                                                      \
  do {                                                                             \
    __builtin_amdgcn_global_load_lds(                                              \
        (AS1 void*)(sgA0 + (size_t)(h) * 128 * K_ + (kt) * 64),                    \
        (AS3 void*)((ubase) + w * 1024), 16, 0, 0);                                \
    __builtin_amdgcn_global_load_lds(                                              \
        (AS1 void*)(sgA1 + (size_t)(h) * 128 * K_ + (kt) * 64),                    \
        (AS3 void*)((ubase) + 8192 + w * 1024), 16, 0, 0);                         \
  } while (0)

#define STAGE_B(h, kt, ubase)                                                      \
  do {                                                                             \
    __builtin_amdgcn_global_load_lds(                                              \
        (AS1 void*)(sgB0 + (size_t)(h) * 128 * K_ + (kt) * 64),                    \
        (AS3 void*)((ubase) + w * 1024), 16, 0, 0);                                \
    __builtin_amdgcn_global_load_lds(                                              \
        (AS1 void*)(sgB1 + (size_t)(h) * 128 * K_ + (kt) * 64),                    \
        (AS3 void*)((ubase) + 8192 + w * 1024), 16, 0, 0);                         \
  } while (0)

__global__ __launch_bounds__(512, 2) void gemm_kernel(
    const unsigned short* __restrict__ xb,
    const unsigned short* __restrict__ wb,
    const float* __restrict__ bias,
    float* __restrict__ out) {
  // LDS map (byte): A(buf,half) = buf*32768 + half*16384        [0, 64K)
  //                 B(buf,half) = 65536 + buf*32768 + half*16384 [64K, 128K)
  __shared__ __attribute__((aligned(16))) char smem[131072];

  const int tid  = threadIdx.x;
  const int w    = tid >> 6;      // 0..7
  const int lane = tid & 63;
  const int q    = lane >> 4;
  const int l16  = lane & 15;
  const int wr   = w >> 2;        // 0..1  (M half: 128 rows)
  const int wc   = w & 3;         // 0..3  (N quarter: 64 cols)

  // XCD-aware bijective swizzle (512 wgs, divisible by 8)
  const int id  = blockIdx.y * 16 + blockIdx.x;   // gridDim = (16, 32)
  const int id2 = (id & 7) * 64 + (id >> 3);
  const int m0  = (id2 >> 4) * 256;
  const int n0  = (id2 & 15) * 256;

  // ---- staging geometry (per stage-unit: 128 rows x 64 k; 2 issues/wave) ----
  // issue i covers unit rows [i*64, i*64+64); this thread handles row rr(+64)
  // at chunk-slot lane&7, which must hold global chunk cg = slot ^ (row&7).
  const int rr = w * 8 + (lane >> 3);                       // 0..63
  const int cg = (lane & 7) ^ ((lane >> 3) & 7);            // row&7 == (lane>>3)&7
  const unsigned short* sgA0 = xb + (size_t)(m0 + rr) * K_ + cg * 8;
  const unsigned short* sgA1 = xb + (size_t)(m0 + 64 + rr) * K_ + cg * 8;
  const unsigned short* sgB0 = wb + (size_t)(n0 + rr) * K_ + cg * 8;
  const unsigned short* sgB1 = wb + (size_t)(n0 + 64 + rr) * K_ + cg * 8;

  // ---- compute-side read bases ----
  const char* pA_base = smem + wr * 16384 + l16 * 128;                    // A(buf0, wr)
  const char* pB_base = smem + 65536 + (wc >> 1) * 16384 +
                        ((wc & 1) * 64 + l16) * 128;                      // B(buf0, wc>>1)
  const int sl0 = ((0 + q) ^ (l16 & 7)) * 16;   // k-step 0: chunks 0..3
  const int sl1 = ((4 + q) ^ (l16 & 7)) * 16;   // k-step 1: chunks 4..7

  f32x4 acc[8][4] = {};

  // ---- prologue: issue units 0.B0 0.B1 0.A0 0.A1 1.B0 1.B1 1.A0 (14 loads) ----
  // vmcnt(6) -> tile 0's 4 units (first 8 loads) complete; 3 units in flight.
  STAGE_B(0, 0, smem + 65536);
  STAGE_B(1, 0, smem + 65536 + 16384);
  STAGE_A(0, 0, smem);
  STAGE_A(1, 0, smem + 16384);
  STAGE_B(0, 1, smem + 65536 + 32768);
  STAGE_B(1, 1, smem + 65536 + 32768 + 16384);
  STAGE_A(0, 1, smem + 32768);
  asm volatile("s_waitcnt vmcnt(6)" ::: "memory");
  __builtin_amdgcn_s_barrier();

  for (int t = 0; t < NT_; ++t) {
    const int curo = (t & 1) * 32768;
    const int nxto = ((t + 1) & 1) * 32768;
    const char* cA = pA_base + curo;
    const char* cB = pB_base + curo;

    bf16x8 a[4][2], b[4][2];

    // ---- ph1: read ALL B + A-low (16 ds_read); stage (t+1).A1 ----
    #pragma unroll
    for (int f = 0; f < 4; ++f) {
      a[f][0] = *(const bf16x8*)(cA + f * 2048 + sl0);
      a[f][1] = *(const bf16x8*)(cA + f * 2048 + sl1);
    }
    #pragma unroll
    for (int j = 0; j < 4; ++j) {
      b[j][0] = *(const bf16x8*)(cB + j * 2048 + sl0);
      b[j][1] = *(const bf16x8*)(cB + j * 2048 + sl1);
    }
    if (t + 1 < NT_) STAGE_A(1, t + 1, smem + nxto + 16384);
    __builtin_amdgcn_s_barrier();
    asm volatile("s_waitcnt lgkmcnt(0)" ::: "memory");
    __builtin_amdgcn_sched_barrier(0);
    __builtin_amdgcn_s_setprio(1);
    #pragma unroll
    for (int f = 0; f < 4; ++f)
      #pragma unroll
      for (int j = 0; j < 2; ++j) {
        acc[f][j] = __builtin_amdgcn_mfma_f32_16x16x32_bf16(a[f][0], b[j][0], acc[f][j], 0, 0, 0);
        acc[f][j] = __builtin_amdgcn_mfma_f32_16x16x32_bf16(a[f][1], b[j][1], acc[f][j], 0, 0, 0);
      }
    __builtin_amdgcn_s_setprio(0);
    __builtin_amdgcn_s_barrier();

    // ---- ph2: stage (t+2).B0; MFMA quadrant (m-low, n-high) ----
    if (t + 2 < NT_) STAGE_B(0, t + 2, smem + 65536 + curo);
    __builtin_amdgcn_s_setprio(1);
    #pragma unroll
    for (int f = 0; f < 4; ++f)
      #pragma unroll
      for (int j = 0; j < 2; ++j) {
        acc[f][2 + j] = __builtin_amdgcn_mfma_f32_16x16x32_bf16(a[f][0], b[2 + j][0], acc[f][2 + j], 0, 0, 0);
        acc[f][2 + j] = __builtin_amdgcn_mfma_f32_16x16x32_bf16(a[f][1], b[2 + j][1], acc[f][2 + j], 0, 0, 0);
      }
    __builtin_amdgcn_s_setprio(0);
    __builtin_amdgcn_s_barrier();

    // ---- ph3: read A-high (8 ds_read, overwrites a); stage (t+2).B1 ----
    #pragma unroll
    for (int f = 0; f < 4; ++f) {
      a[f][0] = *(const bf16x8*)(cA + 8192 + f * 2048 + sl0);
      a[f][1] = *(const bf16x8*)(cA + 8192 + f * 2048 + sl1);
    }
    if (t + 2 < NT_) STAGE_B(1, t + 2, smem + 65536 + curo + 16384);
    __builtin_amdgcn_s_barrier();
    asm volatile("s_waitcnt lgkmcnt(0)" ::: "memory");
    __builtin_amdgcn_sched_barrier(0);
    __builtin_amdgcn_s_setprio(1);
    #pragma unroll
    for (int f = 0; f < 4; ++f)
      #pragma unroll
      for (int j = 0; j < 2; ++j) {
        acc[4 + f][j] = __builtin_amdgcn_mfma_f32_16x16x32_bf16(a[f][0], b[j][0], acc[4 + f][j], 0, 0, 0);
        acc[4 + f][j] = __builtin_amdgcn_mfma_f32_16x16x32_bf16(a[f][1], b[j][1], acc[4 + f][j], 0, 0, 0);
      }
    __builtin_amdgcn_s_setprio(0);
    __builtin_amdgcn_s_barrier();

    // ---- ph4: stage (t+2).A0; MFMA quadrant (m-high, n-high); vmcnt ----
    if (t + 2 < NT_) STAGE_A(0, t + 2, smem + curo);
    __builtin_amdgcn_s_setprio(1);
    #pragma unroll
    for (int f = 0; f < 4; ++f)
      #pragma unroll
      for (int j = 0; j < 2; ++j) {
        acc[4 + f][2 + j] = __builtin_amdgcn_mfma_f32_16x16x32_bf16(a[f][0], b[2 + j][0], acc[4 + f][2 + j], 0, 0, 0);
        acc[4 + f][2 + j] = __builtin_amdgcn_mfma_f32_16x16x32_bf16(a[f][1], b[2 + j][1], acc[4 + f][2 + j], 0, 0, 0);
      }
    __builtin_amdgcn_s_setprio(0);
    if (t + 2 < NT_) {
      asm volatile("s_waitcnt vmcnt(6)" ::: "memory");   // tile t+1 complete; 3 units fly
    } else {
      asm volatile("s_waitcnt vmcnt(0)" ::: "memory");   // drain tail
    }
    __builtin_amdgcn_s_barrier();
  }

  float bv[4];
  #pragma unroll
  for (int j = 0; j < 4; ++j)
    bv[j] = bias[n0 + wc * 64 + j * 16 + l16];

  // C/D layout: col = lane&15, row = (lane>>4)*4 + reg  [m89/m91 verified]
  #pragma unroll
  for (int i = 0; i < 8; ++i) {
    const int mrow = m0 + wr * 128 + i * 16 + q * 4;
    #pragma unroll
    for (int j = 0; j < 4; ++j) {
      const int n = n0 + wc * 64 + j * 16 + l16;
      float* op = out + (size_t)mrow * N_ + n;
      #pragma unroll
      for (int r = 0; r < 4; ++r)
        op[(size_t)r * N_] = acc[i][j][r] + bv[j];
    }
  }
}

extern "C" void kernel_launch(void* const* d_in, const int* in_sizes, int n_in,
                              void* d_out, int out_size, void* d_ws, size_t ws_size,
                              hipStream_t stream) {
  const float* x      = (const float*)d_in[0];
  const int*   qw     = (const int*)d_in[1];
  const float* scales = (const float*)d_in[2];
  const float* zeros  = (const float*)d_in[3];
  const float* ow     = (const float*)d_in[4];
  const float* bias   = (const float*)d_in[5];
  float* out = (float*)d_out;

  unsigned short* xb = (unsigned short*)d_ws;            // 64 MiB
  unsigned short* wb = xb + (size_t)M_ * K_;             // +32 MiB

  cvt_x_kernel<<<(M_ * K_ / 8) / 256, 256, 0, stream>>>((const float4*)x, (ushort8*)xb);
  dequant_kernel<<<(N_ * K_ / 8) / 256, 256, 0, stream>>>((const int4*)qw, scales, zeros, ow,
                                                          (ushort8*)wb);
  dim3 grid(N_ / 256, M_ / 256);
  gemm_kernel<<<grid, 512, 0, stream>>>(xb, wb, bias, out);
}

// Round 5
// 494.810 us; speedup vs baseline: 1.1165x; 1.0023x over previous
//
#include <hip/hip_runtime.h>

#define K_ 4096
#define N_ 4096
#define M_ 8192
#define NOUT_ 128
#define NT_ (K_ / 64)

typedef __bf16 bf16x8 __attribute__((ext_vector_type(8)));
typedef float f32x4 __attribute__((ext_vector_type(4)));
typedef unsigned short ushort8 __attribute__((ext_vector_type(8)));

__device__ __forceinline__ unsigned short f2bf(float f) {
  unsigned u = __builtin_bit_cast(unsigned, f);
  u += 0x7fffu + ((u >> 16) & 1u);   // round-to-nearest-even
  return (unsigned short)(u >> 16);
}

// ---- kernel 1: x fp32 -> bf16 (8 elems/thread) ----
__global__ void cvt_x_kernel(const float4* __restrict__ x4, ushort8* __restrict__ xb) {
  const int t = blockIdx.x * 256 + threadIdx.x;
  float4 a = x4[2 * t];
  float4 b = x4[2 * t + 1];
  ushort8 o;
  o[0] = f2bf(a.x); o[1] = f2bf(a.y); o[2] = f2bf(a.z); o[3] = f2bf(a.w);
  o[4] = f2bf(b.x); o[5] = f2bf(b.y); o[6] = f2bf(b.z); o[7] = f2bf(b.w);
  xb[t] = o;
}

// ---- kernel 2: dequant W + fold outlier weights into last 128 k-columns ----
__global__ void dequant_kernel(const int4* __restrict__ q4,
                               const float* __restrict__ scales,
                               const float* __restrict__ zeros,
                               const float* __restrict__ ow,
                               ushort8* __restrict__ wb) {
  const int t = blockIdx.x * 256 + threadIdx.x;  // N*K/8 threads
  const int n = t >> 9;            // K/8 = 512 chunks per row
  const int k = (t & 511) << 3;
  const int g = k >> 7;            // group = k/128
  const float s = scales[g * N_ + n];
  const float z = zeros[g * N_ + n];
  int4 qa = q4[2 * t], qb = q4[2 * t + 1];
  float f[8];
  f[0] = qa.x * s + z; f[1] = qa.y * s + z; f[2] = qa.z * s + z; f[3] = qa.w * s + z;
  f[4] = qb.x * s + z; f[5] = qb.y * s + z; f[6] = qb.z * s + z; f[7] = qb.w * s + z;
  if (k >= K_ - NOUT_) {
    const float4* o4 = (const float4*)(ow + n * NOUT_ + (k - (K_ - NOUT_)));
    float4 oa = o4[0], ob = o4[1];
    f[0] += oa.x; f[1] += oa.y; f[2] += oa.z; f[3] += oa.w;
    f[4] += ob.x; f[5] += ob.y; f[6] += ob.z; f[7] += ob.w;
  }
  ushort8 r;
  #pragma unroll
  for (int i = 0; i < 8; ++i) r[i] = f2bf(f[i]);
  wb[t] = r;
}

// ---- kernel 3: 256x256 tile, 8-wave (2x4), BK=64, register-pipelined GEMM ----
// Snake quadrant order per K-tile: P0=(m0,j0) P1=(m0,j1) P2=(m1,j1) P3=(m1,j0).
// ds_reads are consumed ONE PHASE LATER (compiler inserts counted lgkmcnt), so
// the LDS pipe drains under the MFMA pipe instead of serializing with it:
//   P0: pre-read  B1[t]      (4)  -> consumed P1,P2
//   P1: post-read A-high[t]  (8)  -> consumed P2,P3   (WAR on regs keeps order)
//   P2: stage (t+2).B units; vmcnt(4) proves tile t+1 landed
//   P3: stage (t+2).A units; post-read A-low[t+1] (8) + B0[t+1] (4)
// WAR ledger (stage of unit X >= 2 phases after X's last ds_read issue):
//   B units last read P0 -> staged P2;  A units last read P1 -> staged P3.
// One barrier/phase, sched_barrier(0) fencing both sides of every barrier.
// Chunk-XOR swizzle identical to the verified kernel (0 bank conflicts).
#define AS1 __attribute__((address_space(1)))
#define AS3 __attribute__((address_space(3)))
#define SB() __builtin_amdgcn_sched_barrier(0)

#define STAGE_A(h, kt, ubase)                                                      \
  do {                                                                             \
    __builtin_amdgcn_global_load_lds(                                              \
        (AS1 void*)(sgA0 + (size_t)(h) * 128 * K_ + (kt) * 64),                    \
        (AS3 void*)((ubase) + w * 1024), 16, 0, 0);                                \
    __builtin_amdgcn_global_load_lds(                                              \
        (AS1 void*)(sgA1 + (size_t)(h) * 128 * K_ + (kt) * 64),                    \
        (AS3 void*)((ubase) + 8192 + w * 1024), 16, 0, 0);                         \
  } while (0)

#define STAGE_B(h, kt, ubase)                                                      \
  do {                                                                             \
    __builtin_amdgcn_global_load_lds(                                              \
        (AS1 void*)(sgB0 + (size_t)(h) * 128 * K_ + (kt) * 64),                    \
        (AS3 void*)((ubase) + w * 1024), 16, 0, 0);                                \
    __builtin_amdgcn_global_load_lds(                                              \
        (AS1 void*)(sgB1 + (size_t)(h) * 128 * K_ + (kt) * 64),                    \
        (AS3 void*)((ubase) + 8192 + w * 1024), 16, 0, 0);                         \
  } while (0)

__global__ __launch_bounds__(512, 2) void gemm_kernel(
    const unsigned short* __restrict__ xb,
    const unsigned short* __restrict__ wb,
    const float* __restrict__ bias,
    float* __restrict__ out) {
  // LDS map (byte): A(buf,unit) = buf*32768 + unit*16384        [0, 64K)
  //                 B(buf,unit) = 65536 + buf*32768 + unit*16384 [64K, 128K)
  __shared__ __attribute__((aligned(16))) char smem[131072];

  const int tid  = threadIdx.x;
  const int w    = tid >> 6;      // 0..7
  const int lane = tid & 63;
  const int q    = lane >> 4;
  const int l16  = lane & 15;
  const int wr   = w >> 2;        // 0..1  (M half: 128 rows = A unit wr)
  const int wc   = w & 3;         // 0..3  (N quarter: 64 cols, B unit wc>>1)

  // XCD-aware bijective swizzle (512 wgs, divisible by 8)
  const int id  = blockIdx.y * 16 + blockIdx.x;   // gridDim = (16, 32)
  const int id2 = (id & 7) * 64 + (id >> 3);
  const int m0  = (id2 >> 4) * 256;
  const int n0  = (id2 & 15) * 256;

  // ---- staging geometry (per unit: 128 rows x 64 k = 16 KiB; 2 issues/wave) ----
  const int rr = w * 8 + (lane >> 3);                       // 0..63
  const int cg = (lane & 7) ^ ((lane >> 3) & 7);            // chunk for this slot
  const unsigned short* sgA0 = xb + (size_t)(m0 + rr) * K_ + cg * 8;
  const unsigned short* sgA1 = xb + (size_t)(m0 + 64 + rr) * K_ + cg * 8;
  const unsigned short* sgB0 = wb + (size_t)(n0 + rr) * K_ + cg * 8;
  const unsigned short* sgB1 = wb + (size_t)(n0 + 64 + rr) * K_ + cg * 8;

  // ---- compute-side read bases ----
  const char* pA_base = smem + wr * 16384 + l16 * 128;
  const char* pB_base = smem + 65536 + (wc >> 1) * 16384 + ((wc & 1) * 64 + l16) * 128;
  const int sl0 = ((0 + q) ^ (l16 & 7)) * 16;
  const int sl1 = ((4 + q) ^ (l16 & 7)) * 16;

  f32x4 acc[8][4] = {};
  bf16x8 aR[4][2];     // current A half (m-low at P0/P1, m-high at P2/P3)
  bf16x8 b0R[2][2];    // B j-pair 0 (cols 0..31 of wave quarter)
  bf16x8 b1R[2][2];    // B j-pair 1 (cols 32..63)

  // ---- prologue: stage tiles 0 and 1 (16 loads); vmcnt(8) -> tile 0 landed ----
  STAGE_B(0, 0, smem + 65536);
  STAGE_B(1, 0, smem + 65536 + 16384);
  STAGE_A(0, 0, smem);
  STAGE_A(1, 0, smem + 16384);
  STAGE_B(0, 1, smem + 65536 + 32768);
  STAGE_B(1, 1, smem + 65536 + 32768 + 16384);
  STAGE_A(0, 1, smem + 32768);
  STAGE_A(1, 1, smem + 32768 + 16384);
  asm volatile("s_waitcnt vmcnt(8)" ::: "memory");
  __builtin_amdgcn_s_barrier();
  SB();
  // prologue reads ("P3[-1]"): A-low[0] + B0[0]
  #pragma unroll
  for (int f = 0; f < 4; ++f) {
    aR[f][0] = *(const bf16x8*)(pA_base + f * 2048 + sl0);
    aR[f][1] = *(const bf16x8*)(pA_base + f * 2048 + sl1);
  }
  #pragma unroll
  for (int j = 0; j < 2; ++j) {
    b0R[j][0] = *(const bf16x8*)(pB_base + j * 2048 + sl0);
    b0R[j][1] = *(const bf16x8*)(pB_base + j * 2048 + sl1);
  }

  for (int t = 0; t < NT_; ++t) {
    const int curo = (t & 1) * 32768;
    const int nxto = ((t + 1) & 1) * 32768;
    const char* cA  = pA_base + curo;
    const char* cB  = pB_base + curo;
    const char* cAn = pA_base + nxto;
    const char* cBn = pB_base + nxto;

    // ---- P0: pre-read B1[t]; MFMA (m0,j0) ----
    #pragma unroll
    for (int j = 0; j < 2; ++j) {
      b1R[j][0] = *(const bf16x8*)(cB + (2 + j) * 2048 + sl0);
      b1R[j][1] = *(const bf16x8*)(cB + (2 + j) * 2048 + sl1);
    }
    __builtin_amdgcn_s_setprio(1);
    #pragma unroll
    for (int f = 0; f < 4; ++f)
      #pragma unroll
      for (int j = 0; j < 2; ++j) {
        acc[f][j] = __builtin_amdgcn_mfma_f32_16x16x32_bf16(aR[f][0], b0R[j][0], acc[f][j], 0, 0, 0);
        acc[f][j] = __builtin_amdgcn_mfma_f32_16x16x32_bf16(aR[f][1], b0R[j][1], acc[f][j], 0, 0, 0);
      }
    __builtin_amdgcn_s_setprio(0);
    SB(); __builtin_amdgcn_s_barrier(); SB();

    // ---- P1: MFMA (m0,j1); post-read A-high[t] into aR ----
    __builtin_amdgcn_s_setprio(1);
    #pragma unroll
    for (int f = 0; f < 4; ++f)
      #pragma unroll
      for (int j = 0; j < 2; ++j) {
        acc[f][2 + j] = __builtin_amdgcn_mfma_f32_16x16x32_bf16(aR[f][0], b1R[j][0], acc[f][2 + j], 0, 0, 0);
        acc[f][2 + j] = __builtin_amdgcn_mfma_f32_16x16x32_bf16(aR[f][1], b1R[j][1], acc[f][2 + j], 0, 0, 0);
      }
    __builtin_amdgcn_s_setprio(0);
    #pragma unroll
    for (int f = 0; f < 4; ++f) {
      aR[f][0] = *(const bf16x8*)(cA + 8192 + f * 2048 + sl0);
      aR[f][1] = *(const bf16x8*)(cA + 8192 + f * 2048 + sl1);
    }
    SB(); __builtin_amdgcn_s_barrier(); SB();

    // ---- P2: stage (t+2).B units; MFMA (m1,j1); vmcnt proves tile t+1 ----
    if (t + 2 < NT_) {
      STAGE_B(0, t + 2, smem + 65536 + curo);
      STAGE_B(1, t + 2, smem + 65536 + curo + 16384);
    }
    __builtin_amdgcn_s_setprio(1);
    #pragma unroll
    for (int f = 0; f < 4; ++f)
      #pragma unroll
      for (int j = 0; j < 2; ++j) {
        acc[4 + f][2 + j] = __builtin_amdgcn_mfma_f32_16x16x32_bf16(aR[f][0], b1R[j][0], acc[4 + f][2 + j], 0, 0, 0);
        acc[4 + f][2 + j] = __builtin_amdgcn_mfma_f32_16x16x32_bf16(aR[f][1], b1R[j][1], acc[4 + f][2 + j], 0, 0, 0);
      }
    __builtin_amdgcn_s_setprio(0);
    if (t + 2 < NT_) {
      asm volatile("s_waitcnt vmcnt(4)" ::: "memory");  // t+1 landed; t+2.B in flight
    } else {
      asm volatile("s_waitcnt vmcnt(0)" ::: "memory");
    }
    SB(); __builtin_amdgcn_s_barrier(); SB();

    // ---- P3: stage (t+2).A units; MFMA (m1,j0); post-read A-low+B0 of t+1 ----
    if (t + 2 < NT_) {
      STAGE_A(0, t + 2, smem + curo);
      STAGE_A(1, t + 2, smem + curo + 16384);
    }
    __builtin_amdgcn_s_setprio(1);
    #pragma unroll
    for (int f = 0; f < 4; ++f)
      #pragma unroll
      for (int j = 0; j < 2; ++j) {
        acc[4 + f][j] = __builtin_amdgcn_mfma_f32_16x16x32_bf16(aR[f][0], b0R[j][0], acc[4 + f][j], 0, 0, 0);
        acc[4 + f][j] = __builtin_amdgcn_mfma_f32_16x16x32_bf16(aR[f][1], b0R[j][1], acc[4 + f][j], 0, 0, 0);
      }
    __builtin_amdgcn_s_setprio(0);
    if (t + 1 < NT_) {
      #pragma unroll
      for (int f = 0; f < 4; ++f) {
        aR[f][0] = *(const bf16x8*)(cAn + f * 2048 + sl0);
        aR[f][1] = *(const bf16x8*)(cAn + f * 2048 + sl1);
      }
      #pragma unroll
      for (int j = 0; j < 2; ++j) {
        b0R[j][0] = *(const bf16x8*)(cBn + j * 2048 + sl0);
        b0R[j][1] = *(const bf16x8*)(cBn + j * 2048 + sl1);
      }
    }
    SB(); __builtin_amdgcn_s_barrier(); SB();
  }

  float bv[4];
  #pragma unroll
  for (int j = 0; j < 4; ++j)
    bv[j] = bias[n0 + wc * 64 + j * 16 + l16];

  // C/D layout: col = lane&15, row = (lane>>4)*4 + reg  [m89/m91 verified]
  #pragma unroll
  for (int i = 0; i < 8; ++i) {
    const int mrow = m0 + wr * 128 + i * 16 + q * 4;
    #pragma unroll
    for (int j = 0; j < 4; ++j) {
      const int n = n0 + wc * 64 + j * 16 + l16;
      float* op = out + (size_t)mrow * N_ + n;
      #pragma unroll
      for (int r = 0; r < 4; ++r)
        op[(size_t)r * N_] = acc[i][j][r] + bv[j];
    }
  }
}

extern "C" void kernel_launch(void* const* d_in, const int* in_sizes, int n_in,
                              void* d_out, int out_size, void* d_ws, size_t ws_size,
                              hipStream_t stream) {
  const float* x      = (const float*)d_in[0];
  const int*   qw     = (const int*)d_in[1];
  const float* scales = (const float*)d_in[2];
  const float* zeros  = (const float*)d_in[3];
  const float* ow     = (const float*)d_in[4];
  const float* bias   = (const float*)d_in[5];
  float* out = (float*)d_out;

  unsigned short* xb = (unsigned short*)d_ws;            // 64 MiB
  unsigned short* wb = xb + (size_t)M_ * K_;             // +32 MiB

  cvt_x_kernel<<<(M_ * K_ / 8) / 256, 256, 0, stream>>>((const float4*)x, (ushort8*)xb);
  dequant_kernel<<<(N_ * K_ / 8) / 256, 256, 0, stream>>>((const int4*)qw, scales, zeros, ow,
                                                          (ushort8*)wb);
  dim3 grid(N_ / 256, M_ / 256);
  gemm_kernel<<<grid, 512, 0, stream>>>(xb, wb, bias, out);
}